// Round 1
// baseline (847.355 us; speedup 1.0000x reference)
//
#include <hip/hip_runtime.h>

#define IN_DIM 4096
#define OUT_DIM 4096
#define M_DIM 8192
#define RANK 32
#define LORA_SCALE 1.0f

typedef __bf16 bf16x8 __attribute__((ext_vector_type(8)));
typedef float f32x4 __attribute__((ext_vector_type(4)));

__device__ __forceinline__ unsigned short f2bf(float f) {
  unsigned u = __builtin_bit_cast(unsigned, f);
  u += 0x7FFF + ((u >> 16) & 1);   // round-to-nearest-even
  return (unsigned short)(u >> 16);
}

// ---------------- prep 1: x f32 -> bf16 ----------------
__global__ void prep_x_kernel(const float* __restrict__ X,
                              unsigned short* __restrict__ Xb) {
  const int stride = gridDim.x * blockDim.x;
  const int total4 = (M_DIM * IN_DIM) / 4;
  for (int i = blockIdx.x * blockDim.x + threadIdx.x; i < total4; i += stride) {
    const float4 v = reinterpret_cast<const float4*>(X)[i];
    ushort4 o;
    o.x = f2bf(v.x); o.y = f2bf(v.y); o.z = f2bf(v.z); o.w = f2bf(v.w);
    reinterpret_cast<ushort4*>(Xb)[i] = o;
  }
}

// ---------------- prep 2: w_eff = bf16(W + A @ B^T * scale) ----------------
// block handles 16 output rows (n); 256 threads sweep k.
__global__ void prep_w_kernel(const float* __restrict__ W,
                              const float* __restrict__ A,
                              const float* __restrict__ B,
                              unsigned short* __restrict__ Wb) {
  __shared__ float sA[16][RANK];
  const int tid = threadIdx.x;
  const int nb = blockIdx.x * 16;
  for (int i = tid; i < 16 * RANK; i += 256) sA[i >> 5][i & 31] = A[nb * RANK + i];
  __syncthreads();
  for (int kk = 0; kk < IN_DIM; kk += 256) {
    const int k = kk + tid;
    float b[RANK];
    const float4* Bv = reinterpret_cast<const float4*>(B + (size_t)k * RANK);
#pragma unroll
    for (int r4 = 0; r4 < RANK / 4; ++r4) {
      const float4 v = Bv[r4];
      b[r4 * 4 + 0] = v.x; b[r4 * 4 + 1] = v.y;
      b[r4 * 4 + 2] = v.z; b[r4 * 4 + 3] = v.w;
    }
#pragma unroll
    for (int nn = 0; nn < 16; ++nn) {
      float d = 0.f;
#pragma unroll
      for (int r = 0; r < RANK; ++r) d += sA[nn][r] * b[r];
      const size_t idx = (size_t)(nb + nn) * IN_DIM + k;
      Wb[idx] = f2bf(W[idx] + LORA_SCALE * d);
    }
  }
}

// ---------------- main GEMM: Y[M][N] = Xb[M][K] * Wb[N][K]^T + bias ----------------
// 128x128 tile, BK=32, 4 waves (2x2), each wave 64x64 via 4x4 frags of 16x16x32 MFMA.
// LDS tiles stored k-chunked [4][128][8] so ds_read_b128 is conflict-free; the
// global_load_lds per-lane SOURCE addresses are permuted to match linear LDS order.
__global__ __launch_bounds__(256) void gemm_kernel(
    const unsigned short* __restrict__ Xb, const unsigned short* __restrict__ Wb,
    const float* __restrict__ bias, float* __restrict__ Y) {
  __shared__ unsigned short sA[4][128][8];   // 8 KB
  __shared__ unsigned short sB[4][128][8];   // 8 KB
  const int tid  = threadIdx.x;
  const int lane = tid & 63;
  const int wid  = tid >> 6;
  const int wr   = wid >> 1, wc = wid & 1;
  const int bRow = blockIdx.y * 128;
  const int bCol = blockIdx.x * 128;

  f32x4 acc[4][4];
#pragma unroll
  for (int m = 0; m < 4; ++m)
#pragma unroll
    for (int n = 0; n < 4; ++n) acc[m][n] = f32x4{0.f, 0.f, 0.f, 0.f};

  // staging: LDS byte off = q*4096 + wid*1024 + lane*16 -> chunk = q*256+wid*64+lane
  // chunk -> kchunk = chunk>>7, row = chunk&127 ; global src = (row, k0 + kchunk*8)
  const int c0 = wid * 64 + lane;
  const int kc0 = c0 >> 7, r0 = c0 & 127;
  const int c1 = 256 + wid * 64 + lane;
  const int kc1 = c1 >> 7, r1 = c1 & 127;

  const unsigned short* gA0 = Xb + (size_t)(bRow + r0) * IN_DIM + kc0 * 8;
  const unsigned short* gA1 = Xb + (size_t)(bRow + r1) * IN_DIM + kc1 * 8;
  const unsigned short* gB0 = Wb + (size_t)(bCol + r0) * IN_DIM + kc0 * 8;
  const unsigned short* gB1 = Wb + (size_t)(bCol + r1) * IN_DIM + kc1 * 8;

  char* ldsA = (char*)&sA[0][0][0];
  char* ldsB = (char*)&sB[0][0][0];
  const int woff = wid * 1024;

  const int kg = lane >> 4, li = lane & 15;

  for (int k0 = 0; k0 < IN_DIM; k0 += 32) {
    __builtin_amdgcn_global_load_lds(
        (const __attribute__((address_space(1))) unsigned int*)gA0,
        (__attribute__((address_space(3))) unsigned int*)(ldsA + woff), 16, 0, 0);
    __builtin_amdgcn_global_load_lds(
        (const __attribute__((address_space(1))) unsigned int*)gA1,
        (__attribute__((address_space(3))) unsigned int*)(ldsA + 4096 + woff), 16, 0, 0);
    __builtin_amdgcn_global_load_lds(
        (const __attribute__((address_space(1))) unsigned int*)gB0,
        (__attribute__((address_space(3))) unsigned int*)(ldsB + woff), 16, 0, 0);
    __builtin_amdgcn_global_load_lds(
        (const __attribute__((address_space(1))) unsigned int*)gB1,
        (__attribute__((address_space(3))) unsigned int*)(ldsB + 4096 + woff), 16, 0, 0);
    gA0 += 32; gA1 += 32; gB0 += 32; gB1 += 32;
    __syncthreads();   // compiler emits s_waitcnt vmcnt(0) before s_barrier

    bf16x8 af[4], bff[4];
#pragma unroll
    for (int m = 0; m < 4; ++m)
      af[m] = *reinterpret_cast<const bf16x8*>(&sA[kg][wr * 64 + m * 16 + li][0]);
#pragma unroll
    for (int n = 0; n < 4; ++n)
      bff[n] = *reinterpret_cast<const bf16x8*>(&sB[kg][wc * 64 + n * 16 + li][0]);
#pragma unroll
    for (int m = 0; m < 4; ++m)
#pragma unroll
      for (int n = 0; n < 4; ++n)
        acc[m][n] = __builtin_amdgcn_mfma_f32_16x16x32_bf16(af[m], bff[n], acc[m][n], 0, 0, 0);
    __syncthreads();
  }

  // epilogue: C/D layout col = lane&15, row = (lane>>4)*4 + j  (m89-verified)
#pragma unroll
  for (int n = 0; n < 4; ++n) {
    const int col = bCol + wc * 64 + n * 16 + li;
    const float bv = bias[col];
#pragma unroll
    for (int m = 0; m < 4; ++m) {
      const int row0 = bRow + wr * 64 + m * 16 + kg * 4;
#pragma unroll
      for (int j = 0; j < 4; ++j)
        Y[(size_t)(row0 + j) * OUT_DIM + col] = acc[m][n][j] + bv;
    }
  }
}

extern "C" void kernel_launch(void* const* d_in, const int* in_sizes, int n_in,
                              void* d_out, int out_size, void* d_ws, size_t ws_size,
                              hipStream_t stream) {
  const float* x    = (const float*)d_in[0];
  const float* w    = (const float*)d_in[1];
  const float* bias = (const float*)d_in[2];
  const float* A    = (const float*)d_in[3];
  const float* B    = (const float*)d_in[4];
  float* y = (float*)d_out;

  const size_t xb_bytes = (size_t)M_DIM * IN_DIM * 2;          // 64 MiB
  const size_t wb_bytes = (size_t)OUT_DIM * IN_DIM * 2;        // 32 MiB
  if (ws_size < xb_bytes + wb_bytes) return;                   // fail visibly if ws too small

  unsigned short* Xb = (unsigned short*)d_ws;
  unsigned short* Wb = (unsigned short*)((char*)d_ws + xb_bytes);

  prep_x_kernel<<<2048, 256, 0, stream>>>(x, Xb);
  prep_w_kernel<<<OUT_DIM / 16, 256, 0, stream>>>(w, A, B, Wb);
  gemm_kernel<<<dim3(OUT_DIM / 128, M_DIM / 128), 256, 0, stream>>>(Xb, Wb, bias, y);
}